// Round 14
// baseline (1122.817 us; speedup 1.0000x reference)
//
#include <hip/hip_runtime.h>
#include <hip/hip_bf16.h>

#define BB 64
#define NN 50
#define TT 30
#define EE 300
#define FN 400
#define AA 200
#define GG 400

typedef __attribute__((ext_vector_type(8))) short bf16x8;
typedef __attribute__((ext_vector_type(4))) float f32x4;

__device__ inline ushort f2bf(float x) {
  __hip_bfloat16 b = __float2bfloat16(x);
  return *(ushort*)&b;
}

__device__ inline float sigf(float x) { return 1.f / (1.f + __expf(-x)); }

// ---------------------------------------------------------------------------
// K_PREP_ALL: one-time weight repacks.
// segments: WhhT | WT2 | vT2 | q/vb | Wih_bf
// ---------------------------------------------------------------------------
__global__ void k_prep_all(
    const float* __restrict__ Whh, const float* __restrict__ cw,
    const float* __restrict__ v, const float* __restrict__ q,
    const float* __restrict__ vb, const float* __restrict__ Wih,
    float* __restrict__ WhhT, __hip_bfloat16* __restrict__ WT2,
    __hip_bfloat16* __restrict__ vT2, float* __restrict__ qp,
    float* __restrict__ vbp, __hip_bfloat16* __restrict__ Wih_bf)
{
  int i = blockIdx.x * 256 + threadIdx.x;
  if (i < 480000) {                      // WhhT fp32 [400 g][1200 j]
    int g = i / 1200, j = i - g * 1200;
    WhhT[i] = Whh[j * 400 + g];
  } else if (i < 910080) {               // WT2 bf16 [30 s][448 f][32 kk]
    int k = i - 480000;
    int kk = k & 31, f = (k >> 5) % 448, s = k / (448 * 32);
    int ko = s / 10, e = (s - ko * 10) * 32 + kk;
    float val = (f < FN && e < EE) ? cw[(ko * EE + e) * FN + f] : 0.f;
    WT2[k] = __float2bfloat16(val);
  } else if (i < 1003264) {              // vT2 bf16 [13 ks][224 a][32 kk]
    int k = i - 910080;
    int kk = k & 31, a = (k >> 5) % 224, ks = k / (224 * 32);
    int e = ks * 32 + kk;
    float val = (a < AA && e < FN) ? v[e * AA + a] : 0.f;
    vT2[k] = __float2bfloat16(val);
  } else if (i < 1003488) {              // qp / vbp
    int k = i - 1003264;
    qp[k]  = k < AA ? q[k]  : 0.f;
    vbp[k] = k < AA ? vb[k] : 0.f;
  } else if (i < 1562592) {              // Wih_bf [1344 j][416 f]
    int k = i - 1003488;
    int j = k / 416, f = k % 416;
    Wih_bf[k] = __float2bfloat16((j < 1200 && f < FN) ? Wih[j * 400 + f] : 0.f);
  }
}

// ---------------------------------------------------------------------------
// K_PREP_EMB: word_emb fp32 [50000][300] -> bf16 [50000][320] (32MB, L3-fits)
// ---------------------------------------------------------------------------
__global__ void k_prep_emb(const float* __restrict__ w, __hip_bfloat16* __restrict__ o) {
  int i = blockIdx.x * 256 + threadIdx.x;   // one 4-col group per thread
  if (i < 50000 * 80) {
    int row = i / 80, cg = i - row * 80;
    ushort4 u4 = make_ushort4(0, 0, 0, 0);
    if (cg < 75) {
      float4 v4 = *(const float4*)(w + (size_t)row * EE + cg * 4);
      u4 = make_ushort4(f2bf(v4.x), f2bf(v4.y), f2bf(v4.z), f2bf(v4.w));
    }
    *(ushort4*)((ushort*)o + (size_t)row * 320 + cg * 4) = u4;
  }
}

// ---------------------------------------------------------------------------
// K_CONV v6 (best measured config): barrier-free MFMA conv.
// Block = 2 titles, 256 thr / 4 waves, acc[4][7]/wave, plain unrolled K-loop
// (compiler pipelines; explicit dbuf measured worse r11/r12). bf16 emb
// gather; E stride 332 (bank conflicts 3.07M->384K); normal C stores (NT
// measured -130us net, r12).
// ---------------------------------------------------------------------------
__global__ __launch_bounds__(256, 2) void k_conv(
    const int* __restrict__ title, const __hip_bfloat16* __restrict__ emb,
    const __hip_bfloat16* __restrict__ WT2, const float* __restrict__ conv_b,
    __hip_bfloat16* __restrict__ C)
{
  __shared__ __align__(16) ushort E[2][34][332];
  __shared__ int words[60];
  const int g = blockIdx.x;       // titles 2g, 2g+1
  const int tid = threadIdx.x;
  const int lane = tid & 63, wn = tid >> 6;
  const int l15 = lane & 15, l4 = lane >> 4;

  if (tid < 60) words[tid] = title[g * 60 + tid];
  for (int idx = tid; idx < 2822; idx += 256)   // zero E
    *(uint4*)((ushort*)E + idx * 8) = make_uint4(0u, 0u, 0u, 0u);
  __syncthreads();
  for (int idx = tid; idx < 2400; idx += 256) {
    int row = idx / 40, c = idx - row * 40;
    int tt = row / 30, w = row - tt * 30;
    *(uint4*)(&E[tt][w + 1][c * 8]) =
        *(const uint4*)((const ushort*)emb + (size_t)words[row] * 320 + c * 8);
  }
  __syncthreads();

  f32x4 acc[4][7];
#pragma unroll
  for (int nt = 0; nt < 7; ++nt) {
    int f = wn * 112 + nt * 16 + l15;
    float bj = (f < FN) ? conv_b[f] : 0.f;
#pragma unroll
    for (int mt = 0; mt < 4; ++mt) {
      acc[mt][nt][0] = bj; acc[mt][nt][1] = bj;
      acc[mt][nt][2] = bj; acc[mt][nt][3] = bj;
    }
  }

  const ushort* Bbase = (const ushort*)WT2 + (size_t)(wn * 112 + l15) * 32 + l4 * 8;

#pragma unroll
  for (int ko = 0; ko < 3; ++ko) {
#pragma unroll
    for (int ks = 0; ks < 10; ++ks) {
      const int s = ko * 10 + ks;
      bf16x8 bq[7];
#pragma unroll
      for (int nt = 0; nt < 7; ++nt)
        bq[nt] = *(const bf16x8*)(Bbase + (size_t)s * 14336 + nt * 512);
      bf16x8 af[4];
#pragma unroll
      for (int mt = 0; mt < 4; ++mt)
        af[mt] = *(const bf16x8*)(&E[mt >> 1][(mt & 1) * 16 + l15 + ko][ks * 32 + l4 * 8]);
#pragma unroll
      for (int nt = 0; nt < 7; ++nt)
#pragma unroll
        for (int mt = 0; mt < 4; ++mt)
          acc[mt][nt] = __builtin_amdgcn_mfma_f32_16x16x32_bf16(af[mt], bq[nt], acc[mt][nt], 0, 0, 0);
    }
  }

#pragma unroll
  for (int mt = 0; mt < 4; ++mt) {
    const int ti = mt >> 1;
    const int tb = (mt & 1) * 16 + l4 * 4;
#pragma unroll
    for (int nt = 0; nt < 7; ++nt) {
      int f = wn * 112 + nt * 16 + l15;
      if (f < 416) {
#pragma unroll
        for (int r = 0; r < 4; ++r) {
          int t = tb + r;
          if (t < TT) {
            float vv = fmaxf(acc[mt][nt][r], 0.f);
            C[((size_t)(g * 2 + ti) * 30 + t) * 416 + f] = __float2bfloat16(vv);
          }
        }
      }
    }
  }
}

// ---------------------------------------------------------------------------
// K_ATTN v2 (r11-measured best): C tile staged through LDS (coalesced 1KB
// loads), V fragments direct from L2-resident vT2.
// ---------------------------------------------------------------------------
__global__ __launch_bounds__(512) void k_attn(
    const __hip_bfloat16* __restrict__ C, const __hip_bfloat16* __restrict__ vT2,
    const float* __restrict__ vbp, const float* __restrict__ qp,
    float* __restrict__ score)
{
  __shared__ __align__(16) ushort Clds[256 * 40];
  __shared__ float sred[2][256];
  const int tid = threadIdx.x;
  const int lane = tid & 63, wid = tid >> 6;
  const int wm = wid >> 1, wn = wid & 1;
  const int l15 = lane & 15, l4 = lane >> 4;
  const size_t row0 = (size_t)blockIdx.x * 256;

  f32x4 acc[4][7];
  float ql[7];
#pragma unroll
  for (int nt = 0; nt < 7; ++nt) {
    int a = wn * 112 + nt * 16 + l15;
    ql[nt] = qp[a];
    float vbv = vbp[a];
#pragma unroll
    for (int mt = 0; mt < 4; ++mt) {
      acc[mt][nt][0] = vbv; acc[mt][nt][1] = vbv;
      acc[mt][nt][2] = vbv; acc[mt][nt][3] = vbv;
    }
  }

  const ushort* Vbase = (const ushort*)vT2 + (size_t)(wn * 112 + l15) * 32 + l4 * 8;

  for (int ks = 0; ks < 13; ++ks) {
    bf16x8 vf[7];
#pragma unroll
    for (int nt = 0; nt < 7; ++nt)
      vf[nt] = *(const bf16x8*)(Vbase + ((size_t)ks * 224 + nt * 16) * 32);
    for (int idx = tid; idx < 1024; idx += 512) {
      int r = idx >> 2, c = idx & 3;
      *(uint4*)(&Clds[r * 40 + c * 8]) =
          *(const uint4*)((const ushort*)C + (row0 + r) * 416 + ks * 32 + c * 8);
    }
    __syncthreads();
    bf16x8 cf[4];
#pragma unroll
    for (int mt = 0; mt < 4; ++mt)
      cf[mt] = *(const bf16x8*)(&Clds[(wm * 64 + mt * 16 + l15) * 40 + l4 * 8]);
#pragma unroll
    for (int nt = 0; nt < 7; ++nt)
#pragma unroll
      for (int mt = 0; mt < 4; ++mt)
        acc[mt][nt] = __builtin_amdgcn_mfma_f32_16x16x32_bf16(cf[mt], vf[nt], acc[mt][nt], 0, 0, 0);
    __syncthreads();
  }

  float sums[4][4];
#pragma unroll
  for (int mt = 0; mt < 4; ++mt)
#pragma unroll
    for (int r = 0; r < 4; ++r) sums[mt][r] = 0.f;
#pragma unroll
  for (int mt = 0; mt < 4; ++mt)
#pragma unroll
    for (int nt = 0; nt < 7; ++nt)
#pragma unroll
      for (int r = 0; r < 4; ++r)
        sums[mt][r] += tanhf(acc[mt][nt][r]) * ql[nt];
#pragma unroll
  for (int mask = 1; mask < 16; mask <<= 1)
#pragma unroll
    for (int mt = 0; mt < 4; ++mt)
#pragma unroll
      for (int r = 0; r < 4; ++r)
        sums[mt][r] += __shfl_xor(sums[mt][r], mask);

  float outv = 0.f;
#pragma unroll
  for (int mt = 0; mt < 4; ++mt)
#pragma unroll
    for (int r = 0; r < 4; ++r)
      if (l15 == mt * 4 + r) outv = sums[mt][r];
  sred[wn][wm * 64 + (l15 >> 2) * 16 + l4 * 4 + (l15 & 3)] = outv;
  __syncthreads();
  if (tid < 256) score[row0 + tid] = sred[0][tid] + sred[1][tid];
}

// ---------------------------------------------------------------------------
// K2: softmax over the N (titles) axis, per (b,t).
// ---------------------------------------------------------------------------
__global__ void k2_softmax_n(const float* __restrict__ score, float* __restrict__ alpha) {
  int i = blockIdx.x * 256 + threadIdx.x;
  if (i >= BB * TT) return;
  int b = i / TT, t = i - b * TT;
  int base = b * (NN * TT) + t;
  float m = -1e30f;
  for (int n = 0; n < NN; ++n) m = fmaxf(m, score[base + n * TT]);
  float s = 0.f;
  for (int n = 0; n < NN; ++n) s += __expf(score[base + n * TT] - m);
  float inv = 1.f / s;
  for (int n = 0; n < NN; ++n)
    alpha[base + n * TT] = __expf(score[base + n * TT] - m) * inv;
}

// ---------------------------------------------------------------------------
// K3: e[bn,f] = sum_t alpha[bn,t] * C[bn,t,f]  -> bf16 [3200][416] padded
// ---------------------------------------------------------------------------
__global__ __launch_bounds__(256) void k3_wsum(
    const float* __restrict__ alpha, const __hip_bfloat16* __restrict__ C,
    __hip_bfloat16* __restrict__ Ebf) {
  __shared__ float al[TT];
  const int bn = blockIdx.x;
  const int tid = threadIdx.x;
  if (tid < TT) al[tid] = alpha[bn * TT + tid];
  __syncthreads();
  for (int f = tid; f < 416; f += 256) {
    float s = 0.f;
    if (f < FN) {
#pragma unroll
      for (int t = 0; t < TT; ++t)
        s = fmaf(al[t], __bfloat162float(C[((size_t)bn * TT + t) * 416 + f]), s);
    }
    Ebf[(size_t)bn * 416 + f] = __float2bfloat16(s);
  }
}

// ---------------------------------------------------------------------------
// K4: gx = e @ W_ih^T + b_ih via bf16 MFMA. M=3200, N=1344(pad), K=416.
// ---------------------------------------------------------------------------
__global__ __launch_bounds__(512) void k4_gx_mfma(
    const __hip_bfloat16* __restrict__ Ebf,   // [3200][416]
    const __hip_bfloat16* __restrict__ Wih,   // [1344][416]
    const float* __restrict__ b_ih,           // [1200]
    float* __restrict__ gx)                   // [3200][1200]
{
  __shared__ __align__(16) ushort Alds[128 * 40];
  __shared__ __align__(16) ushort Blds[448 * 40];
  const int tid = threadIdx.x;
  const int lane = tid & 63, wid = tid >> 6;
  const int wm = wid >> 2, wn = wid & 3;
  const int l15 = lane & 15, l4 = lane >> 4;
  const int mb = blockIdx.x / 3;
  const int nb = blockIdx.x - mb * 3;
  const int row0 = mb * 128;
  const int n0 = nb * 448;

  f32x4 acc[4][7];
#pragma unroll
  for (int nt = 0; nt < 7; ++nt) {
    int j = n0 + wn * 112 + nt * 16 + l15;
    float bj = (j < 1200) ? b_ih[j] : 0.f;
#pragma unroll
    for (int mt = 0; mt < 4; ++mt) {
      acc[mt][nt][0] = bj; acc[mt][nt][1] = bj;
      acc[mt][nt][2] = bj; acc[mt][nt][3] = bj;
    }
  }

  const int ar = tid >> 2, ac = tid & 3;
  for (int ks = 0; ks < 13; ++ks) {
    *(uint4*)(&Alds[ar * 40 + ac * 8]) =
        *(const uint4*)((const ushort*)Ebf + (size_t)(row0 + ar) * 416 + ks * 32 + ac * 8);
    for (int idx = tid; idx < 1792; idx += 512) {
      int r = idx >> 2, c = idx & 3;
      *(uint4*)(&Blds[r * 40 + c * 8]) =
          *(const uint4*)((const ushort*)Wih + (size_t)(n0 + r) * 416 + ks * 32 + c * 8);
    }
    __syncthreads();
    bf16x8 af[4];
#pragma unroll
    for (int mt = 0; mt < 4; ++mt)
      af[mt] = *(const bf16x8*)(&Alds[(wm * 64 + mt * 16 + l15) * 40 + l4 * 8]);
#pragma unroll
    for (int nt = 0; nt < 7; ++nt) {
      bf16x8 bfr = *(const bf16x8*)(&Blds[(wn * 112 + nt * 16 + l15) * 40 + l4 * 8]);
#pragma unroll
      for (int mt = 0; mt < 4; ++mt)
        acc[mt][nt] = __builtin_amdgcn_mfma_f32_16x16x32_bf16(af[mt], bfr, acc[mt][nt], 0, 0, 0);
    }
    __syncthreads();
  }

#pragma unroll
  for (int mt = 0; mt < 4; ++mt) {
    int row = row0 + wm * 64 + mt * 16 + l4 * 4;
#pragma unroll
    for (int nt = 0; nt < 7; ++nt) {
      int j = n0 + wn * 112 + nt * 16 + l15;
      if (j < 1200) {
#pragma unroll
        for (int r = 0; r < 4; ++r)
          gx[(size_t)(row + r) * 1200 + j] = acc[mt][nt][r];
      }
    }
  }
}

// ---------------------------------------------------------------------------
// K5 v3: FUSED single-launch GRU. Block = 2 batches (32 blocks x 320 thr).
// Each block owns its batches' h entirely in LDS -> all 50 steps need only
// __syncthreads() (no grid.sync — measured 7x slower; no 50-launch chain —
// each launch invalidated per-XCD L2, refetching the 1.9MB W every step).
// W_hh^T stays L2-resident ACROSS steps within the kernel. GEMV: 300 threads
// x float4 j-columns, coalesced W loads, LDS-broadcast h.
// ---------------------------------------------------------------------------
__global__ __launch_bounds__(320) void k5_gru(
    const int* __restrict__ user_id, const int* __restrict__ hist_len,
    const float* __restrict__ user_emb,
    const float* __restrict__ WhhT,     // [400 g][1200 j]
    const float* __restrict__ b_hh,     // [1200]
    const float* __restrict__ gx,       // [64][50][1200]
    float* __restrict__ out)            // [64][400]
{
  __shared__ float hl[2][GG];
  __shared__ float gh[2][1200];
  const int blk = blockIdx.x;
  const int b0 = blk * 2;
  const int tid = threadIdx.x;

  for (int i = tid; i < 2 * GG; i += 320) {
    int b = i / GG, g = i - b * GG;
    hl[b][g] = user_emb[(size_t)user_id[b0 + b] * GG + g];
  }
  const int len0 = hist_len[b0];
  const int len1 = hist_len[b0 + 1];

  const int j4 = tid * 4;
  float4 bh4 = make_float4(0.f, 0.f, 0.f, 0.f);
  if (tid < 300) bh4 = *(const float4*)(b_hh + j4);
  __syncthreads();

  for (int step = 0; step < NN; ++step) {
    if (tid < 300) {
      float a0x = 0.f, a0y = 0.f, a0z = 0.f, a0w = 0.f;
      float a1x = 0.f, a1y = 0.f, a1z = 0.f, a1w = 0.f;
      const float* wp = WhhT + j4;
#pragma unroll 2
      for (int g4 = 0; g4 < 100; ++g4) {
        float4 h0v = *(const float4*)(&hl[0][g4 * 4]);   // LDS broadcast
        float4 h1v = *(const float4*)(&hl[1][g4 * 4]);
#pragma unroll
        for (int c = 0; c < 4; ++c) {
          float4 w = *(const float4*)(wp + (size_t)(g4 * 4 + c) * 1200);
          float h0 = (c == 0) ? h0v.x : (c == 1) ? h0v.y : (c == 2) ? h0v.z : h0v.w;
          float h1 = (c == 0) ? h1v.x : (c == 1) ? h1v.y : (c == 2) ? h1v.z : h1v.w;
          a0x = fmaf(w.x, h0, a0x); a0y = fmaf(w.y, h0, a0y);
          a0z = fmaf(w.z, h0, a0z); a0w = fmaf(w.w, h0, a0w);
          a1x = fmaf(w.x, h1, a1x); a1y = fmaf(w.y, h1, a1y);
          a1z = fmaf(w.z, h1, a1z); a1w = fmaf(w.w, h1, a1w);
        }
      }
      *(float4*)(&gh[0][j4]) = make_float4(a0x + bh4.x, a0y + bh4.y, a0z + bh4.z, a0w + bh4.w);
      *(float4*)(&gh[1][j4]) = make_float4(a1x + bh4.x, a1y + bh4.y, a1z + bh4.z, a1w + bh4.w);
    }
    __syncthreads();

    for (int i = tid; i < 800; i += 320) {
      int b = i / 400, g = i - b * 400;
      const float* gxp = gx + ((size_t)(b0 + b) * NN + step) * 1200;
      float xr = gxp[g], xz = gxp[400 + g], xn = gxp[800 + g];
      float hr = gh[b][g], hz = gh[b][400 + g], hn = gh[b][800 + g];
      float r = sigf(xr + hr);
      float z = sigf(xz + hz);
      float nv = tanhf(xn + r * hn);
      float hold = hl[b][g];
      float hnew = (1.f - z) * nv + z * hold;
      int len = b ? len1 : len0;
      if (step < len) hl[b][g] = hnew;
    }
    __syncthreads();
  }

  for (int i = tid; i < 2 * GG; i += 320) {
    int b = i / GG, g = i - b * GG;
    out[(size_t)(b0 + b) * GG + g] = hl[b][g];
  }
}

// ---------------------------------------------------------------------------
extern "C" void kernel_launch(void* const* d_in, const int* in_sizes, int n_in,
                              void* d_out, int out_size, void* d_ws, size_t ws_size,
                              hipStream_t stream) {
  const int*   user_id   = (const int*)d_in[0];
  const int*   title     = (const int*)d_in[1];
  const int*   hist_len  = (const int*)d_in[2];
  const float* word_emb  = (const float*)d_in[3];
  const float* conv_w    = (const float*)d_in[4];
  const float* conv_b    = (const float*)d_in[5];
  const float* v         = (const float*)d_in[6];
  const float* vb        = (const float*)d_in[7];
  const float* q         = (const float*)d_in[8];
  const float* user_emb  = (const float*)d_in[9];
  const float* W_ih      = (const float*)d_in[10];
  const float* W_hh      = (const float*)d_in[11];
  const float* b_ih      = (const float*)d_in[12];
  const float* b_hh      = (const float*)d_in[13];
  float* out = (float*)d_out;

  char* ws = (char*)d_ws;
  size_t off = 0;
  auto take = [&](size_t bytes) {
    char* p = ws + off;
    off = (off + bytes + 255) & ~(size_t)255;
    return p;
  };
  __hip_bfloat16* C      = (__hip_bfloat16*)take((size_t)BB * NN * TT * 416 * 2);  // 79.9MB
  float* score  = (float*)take((size_t)BB * NN * TT * 4);
  float* alpha  = (float*)take((size_t)BB * NN * TT * 4);
  __hip_bfloat16* Ebf    = (__hip_bfloat16*)take((size_t)BB * NN * 416 * 2);
  __hip_bfloat16* Wih_bf = (__hip_bfloat16*)take((size_t)1344 * 416 * 2);
  float* WhhT   = (float*)take((size_t)400 * 1200 * 4);
  float* gx     = (float*)take((size_t)BB * NN * 1200 * 4);
  __hip_bfloat16* emb_bf = (__hip_bfloat16*)take((size_t)50000 * 320 * 2);        // 32MB
  __hip_bfloat16* WT2    = (__hip_bfloat16*)take((size_t)30 * 448 * 32 * 2);      // 860KB
  __hip_bfloat16* vT2    = (__hip_bfloat16*)take((size_t)13 * 224 * 32 * 2);      // 186KB
  float* qp     = (float*)take(224 * 4);
  float* vbp    = (float*)take(224 * 4);
  (void)ws_size;

  k_prep_all<<<6104, 256, 0, stream>>>(W_hh, conv_w, v, q, vb, W_ih,
                                       WhhT, WT2, vT2, qp, vbp, Wih_bf);
  k_prep_emb<<<(50000 * 80 + 255) / 256, 256, 0, stream>>>(word_emb, emb_bf);

  k_conv<<<BB * NN / 2, 256, 0, stream>>>(title, emb_bf, WT2, conv_b, C);
  k_attn<<<BB * NN * TT / 256, 512, 0, stream>>>(C, vT2, vbp, qp, score);
  k2_softmax_n<<<(BB * TT + 255) / 256, 256, 0, stream>>>(score, alpha);
  k3_wsum<<<BB * NN, 256, 0, stream>>>(alpha, C, Ebf);
  k4_gx_mfma<<<75, 512, 0, stream>>>(Ebf, Wih_bf, b_ih, gx);

  k5_gru<<<BB / 2, 320, 0, stream>>>(user_id, hist_len, user_emb, WhhT, b_hh,
                                     gx, out);
}

// Round 15
// 848.897 us; speedup vs baseline: 1.3227x; 1.3227x over previous
//
#include <hip/hip_runtime.h>
#include <hip/hip_bf16.h>

#define BB 64
#define NN 50
#define TT 30
#define EE 300
#define FN 400
#define AA 200
#define GG 400

typedef __attribute__((ext_vector_type(8))) short bf16x8;
typedef __attribute__((ext_vector_type(4))) float f32x4;

__device__ inline ushort f2bf(float x) {
  __hip_bfloat16 b = __float2bfloat16(x);
  return *(ushort*)&b;
}

__device__ inline float sigf(float x) { return 1.f / (1.f + __expf(-x)); }

// ---------------------------------------------------------------------------
// K_PREP_ALL: one-time weight repacks.
// segments: Wpk (g-contiguous) | WT2 | vT2 | q/vb | Wih_bf | h0-init
// ---------------------------------------------------------------------------
__global__ void k_prep_all(
    const float* __restrict__ Whh, const float* __restrict__ cw,
    const float* __restrict__ v, const float* __restrict__ q,
    const float* __restrict__ vb, const float* __restrict__ Wih,
    const int* __restrict__ user_id, const float* __restrict__ user_emb,
    float* __restrict__ Wpk, __hip_bfloat16* __restrict__ WT2,
    __hip_bfloat16* __restrict__ vT2, float* __restrict__ qp,
    float* __restrict__ vbp, __hip_bfloat16* __restrict__ Wih_bf,
    float* __restrict__ h0)
{
  int i = blockIdx.x * 256 + threadIdx.x;
  if (i < 480000) {                      // Wpk fp32 [8 gc][150 jl][400 g]
    int g = i % 400;
    int jl = (i / 400) % 150;
    int gc = i / 60000;
    int gate = jl / 50, gl = jl - gate * 50;
    int j = gate * 400 + gc * 50 + gl;
    Wpk[i] = Whh[j * 400 + g];
  } else if (i < 910080) {               // WT2 bf16 [30 s][448 f][32 kk]
    int k = i - 480000;
    int kk = k & 31, f = (k >> 5) % 448, s = k / (448 * 32);
    int ko = s / 10, e = (s - ko * 10) * 32 + kk;
    float val = (f < FN && e < EE) ? cw[(ko * EE + e) * FN + f] : 0.f;
    WT2[k] = __float2bfloat16(val);
  } else if (i < 1003264) {              // vT2 bf16 [13 ks][224 a][32 kk]
    int k = i - 910080;
    int kk = k & 31, a = (k >> 5) % 224, ks = k / (224 * 32);
    int e = ks * 32 + kk;
    float val = (a < AA && e < FN) ? v[e * AA + a] : 0.f;
    vT2[k] = __float2bfloat16(val);
  } else if (i < 1003488) {              // qp / vbp
    int k = i - 1003264;
    qp[k]  = k < AA ? q[k]  : 0.f;
    vbp[k] = k < AA ? vb[k] : 0.f;
  } else if (i < 1562592) {              // Wih_bf [1344 j][416 f]
    int k = i - 1003488;
    int j = k / 416, f = k % 416;
    Wih_bf[k] = __float2bfloat16((j < 1200 && f < FN) ? Wih[j * 400 + f] : 0.f);
  } else if (i < 1588192) {              // h0 = user_emb[user_id]
    int k = i - 1562592;
    int b = k / GG, g = k - b * GG;
    h0[k] = user_emb[(size_t)user_id[b] * GG + g];
  }
}

// ---------------------------------------------------------------------------
// K_PREP_EMB: word_emb fp32 [50000][300] -> bf16 [50000][320] (32MB, L3-fits)
// ---------------------------------------------------------------------------
__global__ void k_prep_emb(const float* __restrict__ w, __hip_bfloat16* __restrict__ o) {
  int i = blockIdx.x * 256 + threadIdx.x;   // one 4-col group per thread
  if (i < 50000 * 80) {
    int row = i / 80, cg = i - row * 80;
    ushort4 u4 = make_ushort4(0, 0, 0, 0);
    if (cg < 75) {
      float4 v4 = *(const float4*)(w + (size_t)row * EE + cg * 4);
      u4 = make_ushort4(f2bf(v4.x), f2bf(v4.y), f2bf(v4.z), f2bf(v4.w));
    }
    *(ushort4*)((ushort*)o + (size_t)row * 320 + cg * 4) = u4;
  }
}

// ---------------------------------------------------------------------------
// K_CONV: barrier-free MFMA conv (r9-best structure, no occupancy cap —
// the (256,2) VGPR cap measured +12us vs uncapped r9). Block = 2 titles,
// 256 thr / 4 waves, acc[4][7]/wave, plain unrolled K-loop. bf16 emb gather;
// E stride 332 (conflicts 3.07M->384K); normal C stores (NT measured -130us
// net, r12).
// ---------------------------------------------------------------------------
__global__ __launch_bounds__(256) void k_conv(
    const int* __restrict__ title, const __hip_bfloat16* __restrict__ emb,
    const __hip_bfloat16* __restrict__ WT2, const float* __restrict__ conv_b,
    __hip_bfloat16* __restrict__ C)
{
  __shared__ __align__(16) ushort E[2][34][332];
  __shared__ int words[60];
  const int g = blockIdx.x;       // titles 2g, 2g+1
  const int tid = threadIdx.x;
  const int lane = tid & 63, wn = tid >> 6;
  const int l15 = lane & 15, l4 = lane >> 4;

  if (tid < 60) words[tid] = title[g * 60 + tid];
  for (int idx = tid; idx < 2822; idx += 256)   // zero E
    *(uint4*)((ushort*)E + idx * 8) = make_uint4(0u, 0u, 0u, 0u);
  __syncthreads();
  for (int idx = tid; idx < 2400; idx += 256) {
    int row = idx / 40, c = idx - row * 40;
    int tt = row / 30, w = row - tt * 30;
    *(uint4*)(&E[tt][w + 1][c * 8]) =
        *(const uint4*)((const ushort*)emb + (size_t)words[row] * 320 + c * 8);
  }
  __syncthreads();

  f32x4 acc[4][7];
#pragma unroll
  for (int nt = 0; nt < 7; ++nt) {
    int f = wn * 112 + nt * 16 + l15;
    float bj = (f < FN) ? conv_b[f] : 0.f;
#pragma unroll
    for (int mt = 0; mt < 4; ++mt) {
      acc[mt][nt][0] = bj; acc[mt][nt][1] = bj;
      acc[mt][nt][2] = bj; acc[mt][nt][3] = bj;
    }
  }

  const ushort* Bbase = (const ushort*)WT2 + (size_t)(wn * 112 + l15) * 32 + l4 * 8;

#pragma unroll
  for (int ko = 0; ko < 3; ++ko) {
#pragma unroll
    for (int ks = 0; ks < 10; ++ks) {
      const int s = ko * 10 + ks;
      bf16x8 bq[7];
#pragma unroll
      for (int nt = 0; nt < 7; ++nt)
        bq[nt] = *(const bf16x8*)(Bbase + (size_t)s * 14336 + nt * 512);
      bf16x8 af[4];
#pragma unroll
      for (int mt = 0; mt < 4; ++mt)
        af[mt] = *(const bf16x8*)(&E[mt >> 1][(mt & 1) * 16 + l15 + ko][ks * 32 + l4 * 8]);
#pragma unroll
      for (int nt = 0; nt < 7; ++nt)
#pragma unroll
        for (int mt = 0; mt < 4; ++mt)
          acc[mt][nt] = __builtin_amdgcn_mfma_f32_16x16x32_bf16(af[mt], bq[nt], acc[mt][nt], 0, 0, 0);
    }
  }

#pragma unroll
  for (int mt = 0; mt < 4; ++mt) {
    const int ti = mt >> 1;
    const int tb = (mt & 1) * 16 + l4 * 4;
#pragma unroll
    for (int nt = 0; nt < 7; ++nt) {
      int f = wn * 112 + nt * 16 + l15;
      if (f < 416) {
#pragma unroll
        for (int r = 0; r < 4; ++r) {
          int t = tb + r;
          if (t < TT) {
            float vv = fmaxf(acc[mt][nt][r], 0.f);
            C[((size_t)(g * 2 + ti) * 30 + t) * 416 + f] = __float2bfloat16(vv);
          }
        }
      }
    }
  }
}

// ---------------------------------------------------------------------------
// K_ATTN v2 (r11-measured best): C tile staged through LDS (coalesced 1KB
// loads), V fragments direct from L2-resident vT2.
// ---------------------------------------------------------------------------
__global__ __launch_bounds__(512) void k_attn(
    const __hip_bfloat16* __restrict__ C, const __hip_bfloat16* __restrict__ vT2,
    const float* __restrict__ vbp, const float* __restrict__ qp,
    float* __restrict__ score)
{
  __shared__ __align__(16) ushort Clds[256 * 40];
  __shared__ float sred[2][256];
  const int tid = threadIdx.x;
  const int lane = tid & 63, wid = tid >> 6;
  const int wm = wid >> 1, wn = wid & 1;
  const int l15 = lane & 15, l4 = lane >> 4;
  const size_t row0 = (size_t)blockIdx.x * 256;

  f32x4 acc[4][7];
  float ql[7];
#pragma unroll
  for (int nt = 0; nt < 7; ++nt) {
    int a = wn * 112 + nt * 16 + l15;
    ql[nt] = qp[a];
    float vbv = vbp[a];
#pragma unroll
    for (int mt = 0; mt < 4; ++mt) {
      acc[mt][nt][0] = vbv; acc[mt][nt][1] = vbv;
      acc[mt][nt][2] = vbv; acc[mt][nt][3] = vbv;
    }
  }

  const ushort* Vbase = (const ushort*)vT2 + (size_t)(wn * 112 + l15) * 32 + l4 * 8;

  for (int ks = 0; ks < 13; ++ks) {
    bf16x8 vf[7];
#pragma unroll
    for (int nt = 0; nt < 7; ++nt)
      vf[nt] = *(const bf16x8*)(Vbase + ((size_t)ks * 224 + nt * 16) * 32);
    for (int idx = tid; idx < 1024; idx += 512) {
      int r = idx >> 2, c = idx & 3;
      *(uint4*)(&Clds[r * 40 + c * 8]) =
          *(const uint4*)((const ushort*)C + (row0 + r) * 416 + ks * 32 + c * 8);
    }
    __syncthreads();
    bf16x8 cf[4];
#pragma unroll
    for (int mt = 0; mt < 4; ++mt)
      cf[mt] = *(const bf16x8*)(&Clds[(wm * 64 + mt * 16 + l15) * 40 + l4 * 8]);
#pragma unroll
    for (int nt = 0; nt < 7; ++nt)
#pragma unroll
      for (int mt = 0; mt < 4; ++mt)
        acc[mt][nt] = __builtin_amdgcn_mfma_f32_16x16x32_bf16(cf[mt], vf[nt], acc[mt][nt], 0, 0, 0);
    __syncthreads();
  }

  float sums[4][4];
#pragma unroll
  for (int mt = 0; mt < 4; ++mt)
#pragma unroll
    for (int r = 0; r < 4; ++r) sums[mt][r] = 0.f;
#pragma unroll
  for (int mt = 0; mt < 4; ++mt)
#pragma unroll
    for (int nt = 0; nt < 7; ++nt)
#pragma unroll
      for (int r = 0; r < 4; ++r)
        sums[mt][r] += tanhf(acc[mt][nt][r]) * ql[nt];
#pragma unroll
  for (int mask = 1; mask < 16; mask <<= 1)
#pragma unroll
    for (int mt = 0; mt < 4; ++mt)
#pragma unroll
      for (int r = 0; r < 4; ++r)
        sums[mt][r] += __shfl_xor(sums[mt][r], mask);

  float outv = 0.f;
#pragma unroll
  for (int mt = 0; mt < 4; ++mt)
#pragma unroll
    for (int r = 0; r < 4; ++r)
      if (l15 == mt * 4 + r) outv = sums[mt][r];
  sred[wn][wm * 64 + (l15 >> 2) * 16 + l4 * 4 + (l15 & 3)] = outv;
  __syncthreads();
  if (tid < 256) score[row0 + tid] = sred[0][tid] + sred[1][tid];
}

// ---------------------------------------------------------------------------
// K2: softmax over the N (titles) axis, per (b,t).
// ---------------------------------------------------------------------------
__global__ void k2_softmax_n(const float* __restrict__ score, float* __restrict__ alpha) {
  int i = blockIdx.x * 256 + threadIdx.x;
  if (i >= BB * TT) return;
  int b = i / TT, t = i - b * TT;
  int base = b * (NN * TT) + t;
  float m = -1e30f;
  for (int n = 0; n < NN; ++n) m = fmaxf(m, score[base + n * TT]);
  float s = 0.f;
  for (int n = 0; n < NN; ++n) s += __expf(score[base + n * TT] - m);
  float inv = 1.f / s;
  for (int n = 0; n < NN; ++n)
    alpha[base + n * TT] = __expf(score[base + n * TT] - m) * inv;
}

// ---------------------------------------------------------------------------
// K3: e[bn,f] = sum_t alpha[bn,t] * C[bn,t,f]  -> bf16 [3200][416] padded
// ---------------------------------------------------------------------------
__global__ __launch_bounds__(256) void k3_wsum(
    const float* __restrict__ alpha, const __hip_bfloat16* __restrict__ C,
    __hip_bfloat16* __restrict__ Ebf) {
  __shared__ float al[TT];
  const int bn = blockIdx.x;
  const int tid = threadIdx.x;
  if (tid < TT) al[tid] = alpha[bn * TT + tid];
  __syncthreads();
  for (int f = tid; f < 416; f += 256) {
    float s = 0.f;
    if (f < FN) {
#pragma unroll
      for (int t = 0; t < TT; ++t)
        s = fmaf(al[t], __bfloat162float(C[((size_t)bn * TT + t) * 416 + f]), s);
    }
    Ebf[(size_t)bn * 416 + f] = __float2bfloat16(s);
  }
}

// ---------------------------------------------------------------------------
// K4: gx = e @ W_ih^T + b_ih via bf16 MFMA. M=3200, N=1344(pad), K=416.
// ---------------------------------------------------------------------------
__global__ __launch_bounds__(512) void k4_gx_mfma(
    const __hip_bfloat16* __restrict__ Ebf,   // [3200][416]
    const __hip_bfloat16* __restrict__ Wih,   // [1344][416]
    const float* __restrict__ b_ih,           // [1200]
    float* __restrict__ gx)                   // [3200][1200]
{
  __shared__ __align__(16) ushort Alds[128 * 40];
  __shared__ __align__(16) ushort Blds[448 * 40];
  const int tid = threadIdx.x;
  const int lane = tid & 63, wid = tid >> 6;
  const int wm = wid >> 2, wn = wid & 3;
  const int l15 = lane & 15, l4 = lane >> 4;
  const int mb = blockIdx.x / 3;
  const int nb = blockIdx.x - mb * 3;
  const int row0 = mb * 128;
  const int n0 = nb * 448;

  f32x4 acc[4][7];
#pragma unroll
  for (int nt = 0; nt < 7; ++nt) {
    int j = n0 + wn * 112 + nt * 16 + l15;
    float bj = (j < 1200) ? b_ih[j] : 0.f;
#pragma unroll
    for (int mt = 0; mt < 4; ++mt) {
      acc[mt][nt][0] = bj; acc[mt][nt][1] = bj;
      acc[mt][nt][2] = bj; acc[mt][nt][3] = bj;
    }
  }

  const int ar = tid >> 2, ac = tid & 3;
  for (int ks = 0; ks < 13; ++ks) {
    *(uint4*)(&Alds[ar * 40 + ac * 8]) =
        *(const uint4*)((const ushort*)Ebf + (size_t)(row0 + ar) * 416 + ks * 32 + ac * 8);
    for (int idx = tid; idx < 1792; idx += 512) {
      int r = idx >> 2, c = idx & 3;
      *(uint4*)(&Blds[r * 40 + c * 8]) =
          *(const uint4*)((const ushort*)Wih + (size_t)(n0 + r) * 416 + ks * 32 + c * 8);
    }
    __syncthreads();
    bf16x8 af[4];
#pragma unroll
    for (int mt = 0; mt < 4; ++mt)
      af[mt] = *(const bf16x8*)(&Alds[(wm * 64 + mt * 16 + l15) * 40 + l4 * 8]);
#pragma unroll
    for (int nt = 0; nt < 7; ++nt) {
      bf16x8 bfr = *(const bf16x8*)(&Blds[(wn * 112 + nt * 16 + l15) * 40 + l4 * 8]);
#pragma unroll
      for (int mt = 0; mt < 4; ++mt)
        acc[mt][nt] = __builtin_amdgcn_mfma_f32_16x16x32_bf16(af[mt], bfr, acc[mt][nt], 0, 0, 0);
    }
    __syncthreads();
  }

#pragma unroll
  for (int mt = 0; mt < 4; ++mt) {
    int row = row0 + wm * 64 + mt * 16 + l4 * 4;
#pragma unroll
    for (int nt = 0; nt < 7; ++nt) {
      int j = n0 + wn * 112 + nt * 16 + l15;
      if (j < 1200) {
#pragma unroll
        for (int r = 0; r < 4; ++r)
          gx[(size_t)(row + r) * 1200 + j] = acc[mt][nt][r];
      }
    }
  }
}

// ---------------------------------------------------------------------------
// GRU step v3: 256-block chain (proven best structure) with wide-instruction
// GEMV. Wpk is g-contiguous: each thread reads its 1600B W row as 100 float4
// (8x fewer VMEM instr than the strided layout; L2-hot, L1 catches row
// reuse). h read as block-uniform float4 global loads (one L1-broadcast
// request per wave — removes the 800-instr LDS broadcast storm that bound
// the old chain). 4 independent FMA chains. Final step writes out directly.
// ---------------------------------------------------------------------------
__global__ __launch_bounds__(256) void k5_step(
    const float* __restrict__ h_prev, float* __restrict__ h_next,
    const float* __restrict__ Wpk,    // [8 gc][150 jl][400 g]
    const float* __restrict__ b_hh,
    const float* __restrict__ gx, const int* __restrict__ hist_len,
    float* __restrict__ out, int step)
{
  const int gc = blockIdx.x & 7;
  const int bg = blockIdx.x >> 3;
  const int tid = threadIdx.x;
  __shared__ float ghl[2][3][50];

  if (tid < 150) {
    const float* h0p = h_prev + (size_t)(2 * bg) * GG;   // block-uniform
    const float* h1p = h0p + GG;
    const float* wp = Wpk + ((size_t)gc * 150 + tid) * 400;
    float a00 = 0.f, a01 = 0.f, a10 = 0.f, a11 = 0.f;
#pragma unroll 8
    for (int g4 = 0; g4 < 100; ++g4) {
      float4 w  = *(const float4*)(wp + g4 * 4);
      float4 ha = *(const float4*)(h0p + g4 * 4);        // uniform -> L1 bcast
      float4 hb = *(const float4*)(h1p + g4 * 4);
      a00 = fmaf(w.x, ha.x, a00); a01 = fmaf(w.y, ha.y, a01);
      a00 = fmaf(w.z, ha.z, a00); a01 = fmaf(w.w, ha.w, a01);
      a10 = fmaf(w.x, hb.x, a10); a11 = fmaf(w.y, hb.y, a11);
      a10 = fmaf(w.z, hb.z, a10); a11 = fmaf(w.w, hb.w, a11);
    }
    int gate = tid / 50, gl = tid - gate * 50;
    float bb = b_hh[gate * 400 + gc * 50 + gl];
    ghl[0][gate][gl] = a00 + a01 + bb;
    ghl[1][gate][gl] = a10 + a11 + bb;
  }
  __syncthreads();

  if (tid < 100) {
    int b = tid / 50, gl = tid - (tid / 50) * 50;
    int babs = 2 * bg + b;
    int g = gc * 50 + gl;
    const float* gxp = gx + ((size_t)babs * NN + step) * 1200;
    float xr = gxp[g], xz = gxp[400 + g], xn = gxp[800 + g];
    float hr = ghl[b][0][gl], hz = ghl[b][1][gl], hn = ghl[b][2][gl];
    float r = sigf(xr + hr);
    float z = sigf(xz + hz);
    float nv = tanhf(xn + r * hn);
    float hold = h_prev[(size_t)babs * GG + g];
    float hnew = (1.f - z) * nv + z * hold;
    float hres = (step < hist_len[babs]) ? hnew : hold;
    h_next[(size_t)babs * GG + g] = hres;
    if (step == NN - 1) out[(size_t)babs * GG + g] = hres;
  }
}

// ---------------------------------------------------------------------------
extern "C" void kernel_launch(void* const* d_in, const int* in_sizes, int n_in,
                              void* d_out, int out_size, void* d_ws, size_t ws_size,
                              hipStream_t stream) {
  const int*   user_id   = (const int*)d_in[0];
  const int*   title     = (const int*)d_in[1];
  const int*   hist_len  = (const int*)d_in[2];
  const float* word_emb  = (const float*)d_in[3];
  const float* conv_w    = (const float*)d_in[4];
  const float* conv_b    = (const float*)d_in[5];
  const float* v         = (const float*)d_in[6];
  const float* vb        = (const float*)d_in[7];
  const float* q         = (const float*)d_in[8];
  const float* user_emb  = (const float*)d_in[9];
  const float* W_ih      = (const float*)d_in[10];
  const float* W_hh      = (const float*)d_in[11];
  const float* b_ih      = (const float*)d_in[12];
  const float* b_hh      = (const float*)d_in[13];
  float* out = (float*)d_out;

  char* ws = (char*)d_ws;
  size_t off = 0;
  auto take = [&](size_t bytes) {
    char* p = ws + off;
    off = (off + bytes + 255) & ~(size_t)255;
    return p;
  };
  __hip_bfloat16* C      = (__hip_bfloat16*)take((size_t)BB * NN * TT * 416 * 2);  // 79.9MB
  float* score  = (float*)take((size_t)BB * NN * TT * 4);
  float* alpha  = (float*)take((size_t)BB * NN * TT * 4);
  __hip_bfloat16* Ebf    = (__hip_bfloat16*)take((size_t)BB * NN * 416 * 2);
  __hip_bfloat16* Wih_bf = (__hip_bfloat16*)take((size_t)1344 * 416 * 2);
  float* Wpk    = (float*)take((size_t)8 * 150 * 400 * 4);
  float* gx     = (float*)take((size_t)BB * NN * 1200 * 4);
  float* h0     = (float*)take((size_t)BB * GG * 4);
  float* h1     = (float*)take((size_t)BB * GG * 4);
  __hip_bfloat16* emb_bf = (__hip_bfloat16*)take((size_t)50000 * 320 * 2);        // 32MB
  __hip_bfloat16* WT2    = (__hip_bfloat16*)take((size_t)30 * 448 * 32 * 2);      // 860KB
  __hip_bfloat16* vT2    = (__hip_bfloat16*)take((size_t)13 * 224 * 32 * 2);      // 186KB
  float* qp     = (float*)take(224 * 4);
  float* vbp    = (float*)take(224 * 4);
  (void)ws_size;

  k_prep_all<<<6204, 256, 0, stream>>>(W_hh, conv_w, v, q, vb, W_ih, user_id,
                                       user_emb, Wpk, WT2, vT2, qp, vbp,
                                       Wih_bf, h0);
  k_prep_emb<<<(50000 * 80 + 255) / 256, 256, 0, stream>>>(word_emb, emb_bf);

  k_conv<<<BB * NN / 2, 256, 0, stream>>>(title, emb_bf, WT2, conv_b, C);
  k_attn<<<BB * NN * TT / 256, 512, 0, stream>>>(C, vT2, vbp, qp, score);
  k2_softmax_n<<<(BB * TT + 255) / 256, 256, 0, stream>>>(score, alpha);
  k3_wsum<<<BB * NN, 256, 0, stream>>>(alpha, C, Ebf);
  k4_gx_mfma<<<75, 512, 0, stream>>>(Ebf, Wih_bf, b_ih, gx);

  float* hbuf[2] = {h0, h1};
  for (int step = 0; step < NN; ++step) {
    k5_step<<<256, 256, 0, stream>>>(hbuf[step & 1], hbuf[(step + 1) & 1],
                                     Wpk, b_hh, gx, hist_len, out, step);
  }
}

// Round 16
// 848.467 us; speedup vs baseline: 1.3233x; 1.0005x over previous
//
#include <hip/hip_runtime.h>
#include <hip/hip_bf16.h>

#define BB 64
#define NN 50
#define TT 30
#define EE 300
#define FN 400
#define AA 200
#define GG 400

typedef __attribute__((ext_vector_type(8))) short bf16x8;
typedef __attribute__((ext_vector_type(4))) float f32x4;

__device__ inline ushort f2bf(float x) {
  __hip_bfloat16 b = __float2bfloat16(x);
  return *(ushort*)&b;
}

__device__ inline float sigf(float x) { return 1.f / (1.f + __expf(-x)); }

// ---------------------------------------------------------------------------
// K_PREP_ALL: one-time weight repacks.
// segments: Wpk (g-contiguous) | WT2 | vT2 | q/vb | Wih_bf | h0-init
// ---------------------------------------------------------------------------
__global__ void k_prep_all(
    const float* __restrict__ Whh, const float* __restrict__ cw,
    const float* __restrict__ v, const float* __restrict__ q,
    const float* __restrict__ vb, const float* __restrict__ Wih,
    const int* __restrict__ user_id, const float* __restrict__ user_emb,
    float* __restrict__ Wpk, __hip_bfloat16* __restrict__ WT2,
    __hip_bfloat16* __restrict__ vT2, float* __restrict__ qp,
    float* __restrict__ vbp, __hip_bfloat16* __restrict__ Wih_bf,
    float* __restrict__ h0)
{
  int i = blockIdx.x * 256 + threadIdx.x;
  if (i < 480000) {                      // Wpk fp32 [8 gc][150 jl][400 g]
    int g = i % 400;
    int jl = (i / 400) % 150;
    int gc = i / 60000;
    int gate = jl / 50, gl = jl - gate * 50;
    int j = gate * 400 + gc * 50 + gl;
    Wpk[i] = Whh[j * 400 + g];
  } else if (i < 910080) {               // WT2 bf16 [30 s][448 f][32 kk]
    int k = i - 480000;
    int kk = k & 31, f = (k >> 5) % 448, s = k / (448 * 32);
    int ko = s / 10, e = (s - ko * 10) * 32 + kk;
    float val = (f < FN && e < EE) ? cw[(ko * EE + e) * FN + f] : 0.f;
    WT2[k] = __float2bfloat16(val);
  } else if (i < 1003264) {              // vT2 bf16 [13 ks][224 a][32 kk]
    int k = i - 910080;
    int kk = k & 31, a = (k >> 5) % 224, ks = k / (224 * 32);
    int e = ks * 32 + kk;
    float val = (a < AA && e < FN) ? v[e * AA + a] : 0.f;
    vT2[k] = __float2bfloat16(val);
  } else if (i < 1003488) {              // qp / vbp
    int k = i - 1003264;
    qp[k]  = k < AA ? q[k]  : 0.f;
    vbp[k] = k < AA ? vb[k] : 0.f;
  } else if (i < 1562592) {              // Wih_bf [1344 j][416 f]
    int k = i - 1003488;
    int j = k / 416, f = k % 416;
    Wih_bf[k] = __float2bfloat16((j < 1200 && f < FN) ? Wih[j * 400 + f] : 0.f);
  } else if (i < 1588192) {              // h0 = user_emb[user_id]
    int k = i - 1562592;
    int b = k / GG, g = k - b * GG;
    h0[k] = user_emb[(size_t)user_id[b] * GG + g];
  }
}

// ---------------------------------------------------------------------------
// K_PREP_EMB: word_emb fp32 [50000][300] -> bf16 [50000][320] (32MB, L3-fits)
// ---------------------------------------------------------------------------
__global__ void k_prep_emb(const float* __restrict__ w, __hip_bfloat16* __restrict__ o) {
  int i = blockIdx.x * 256 + threadIdx.x;   // one 4-col group per thread
  if (i < 50000 * 80) {
    int row = i / 80, cg = i - row * 80;
    ushort4 u4 = make_ushort4(0, 0, 0, 0);
    if (cg < 75) {
      float4 v4 = *(const float4*)(w + (size_t)row * EE + cg * 4);
      u4 = make_ushort4(f2bf(v4.x), f2bf(v4.y), f2bf(v4.z), f2bf(v4.w));
    }
    *(ushort4*)((ushort*)o + (size_t)row * 320 + cg * 4) = u4;
  }
}

// ---------------------------------------------------------------------------
// K_CONV: barrier-free MFMA conv (r9-best structure, no occupancy cap —
// the (256,2) VGPR cap measured +12us vs uncapped r9). Block = 2 titles,
// 256 thr / 4 waves, acc[4][7]/wave, plain unrolled K-loop. bf16 emb gather;
// E stride 332 (conflicts 3.07M->384K); normal C stores (NT measured -130us
// net, r12).
// ---------------------------------------------------------------------------
__global__ __launch_bounds__(256) void k_conv(
    const int* __restrict__ title, const __hip_bfloat16* __restrict__ emb,
    const __hip_bfloat16* __restrict__ WT2, const float* __restrict__ conv_b,
    __hip_bfloat16* __restrict__ C)
{
  __shared__ __align__(16) ushort E[2][34][332];
  __shared__ int words[60];
  const int g = blockIdx.x;       // titles 2g, 2g+1
  const int tid = threadIdx.x;
  const int lane = tid & 63, wn = tid >> 6;
  const int l15 = lane & 15, l4 = lane >> 4;

  if (tid < 60) words[tid] = title[g * 60 + tid];
  for (int idx = tid; idx < 2822; idx += 256)   // zero E
    *(uint4*)((ushort*)E + idx * 8) = make_uint4(0u, 0u, 0u, 0u);
  __syncthreads();
  for (int idx = tid; idx < 2400; idx += 256) {
    int row = idx / 40, c = idx - row * 40;
    int tt = row / 30, w = row - tt * 30;
    *(uint4*)(&E[tt][w + 1][c * 8]) =
        *(const uint4*)((const ushort*)emb + (size_t)words[row] * 320 + c * 8);
  }
  __syncthreads();

  f32x4 acc[4][7];
#pragma unroll
  for (int nt = 0; nt < 7; ++nt) {
    int f = wn * 112 + nt * 16 + l15;
    float bj = (f < FN) ? conv_b[f] : 0.f;
#pragma unroll
    for (int mt = 0; mt < 4; ++mt) {
      acc[mt][nt][0] = bj; acc[mt][nt][1] = bj;
      acc[mt][nt][2] = bj; acc[mt][nt][3] = bj;
    }
  }

  const ushort* Bbase = (const ushort*)WT2 + (size_t)(wn * 112 + l15) * 32 + l4 * 8;

#pragma unroll
  for (int ko = 0; ko < 3; ++ko) {
#pragma unroll
    for (int ks = 0; ks < 10; ++ks) {
      const int s = ko * 10 + ks;
      bf16x8 bq[7];
#pragma unroll
      for (int nt = 0; nt < 7; ++nt)
        bq[nt] = *(const bf16x8*)(Bbase + (size_t)s * 14336 + nt * 512);
      bf16x8 af[4];
#pragma unroll
      for (int mt = 0; mt < 4; ++mt)
        af[mt] = *(const bf16x8*)(&E[mt >> 1][(mt & 1) * 16 + l15 + ko][ks * 32 + l4 * 8]);
#pragma unroll
      for (int nt = 0; nt < 7; ++nt)
#pragma unroll
        for (int mt = 0; mt < 4; ++mt)
          acc[mt][nt] = __builtin_amdgcn_mfma_f32_16x16x32_bf16(af[mt], bq[nt], acc[mt][nt], 0, 0, 0);
    }
  }

#pragma unroll
  for (int mt = 0; mt < 4; ++mt) {
    const int ti = mt >> 1;
    const int tb = (mt & 1) * 16 + l4 * 4;
#pragma unroll
    for (int nt = 0; nt < 7; ++nt) {
      int f = wn * 112 + nt * 16 + l15;
      if (f < 416) {
#pragma unroll
        for (int r = 0; r < 4; ++r) {
          int t = tb + r;
          if (t < TT) {
            float vv = fmaxf(acc[mt][nt][r], 0.f);
            C[((size_t)(g * 2 + ti) * 30 + t) * 416 + f] = __float2bfloat16(vv);
          }
        }
      }
    }
  }
}

// ---------------------------------------------------------------------------
// K_ATTN v2 (r11-measured best): C tile staged through LDS (coalesced 1KB
// loads), V fragments direct from L2-resident vT2.
// ---------------------------------------------------------------------------
__global__ __launch_bounds__(512) void k_attn(
    const __hip_bfloat16* __restrict__ C, const __hip_bfloat16* __restrict__ vT2,
    const float* __restrict__ vbp, const float* __restrict__ qp,
    float* __restrict__ score)
{
  __shared__ __align__(16) ushort Clds[256 * 40];
  __shared__ float sred[2][256];
  const int tid = threadIdx.x;
  const int lane = tid & 63, wid = tid >> 6;
  const int wm = wid >> 1, wn = wid & 1;
  const int l15 = lane & 15, l4 = lane >> 4;
  const size_t row0 = (size_t)blockIdx.x * 256;

  f32x4 acc[4][7];
  float ql[7];
#pragma unroll
  for (int nt = 0; nt < 7; ++nt) {
    int a = wn * 112 + nt * 16 + l15;
    ql[nt] = qp[a];
    float vbv = vbp[a];
#pragma unroll
    for (int mt = 0; mt < 4; ++mt) {
      acc[mt][nt][0] = vbv; acc[mt][nt][1] = vbv;
      acc[mt][nt][2] = vbv; acc[mt][nt][3] = vbv;
    }
  }

  const ushort* Vbase = (const ushort*)vT2 + (size_t)(wn * 112 + l15) * 32 + l4 * 8;

  for (int ks = 0; ks < 13; ++ks) {
    bf16x8 vf[7];
#pragma unroll
    for (int nt = 0; nt < 7; ++nt)
      vf[nt] = *(const bf16x8*)(Vbase + ((size_t)ks * 224 + nt * 16) * 32);
    for (int idx = tid; idx < 1024; idx += 512) {
      int r = idx >> 2, c = idx & 3;
      *(uint4*)(&Clds[r * 40 + c * 8]) =
          *(const uint4*)((const ushort*)C + (row0 + r) * 416 + ks * 32 + c * 8);
    }
    __syncthreads();
    bf16x8 cf[4];
#pragma unroll
    for (int mt = 0; mt < 4; ++mt)
      cf[mt] = *(const bf16x8*)(&Clds[(wm * 64 + mt * 16 + l15) * 40 + l4 * 8]);
#pragma unroll
    for (int nt = 0; nt < 7; ++nt)
#pragma unroll
      for (int mt = 0; mt < 4; ++mt)
        acc[mt][nt] = __builtin_amdgcn_mfma_f32_16x16x32_bf16(cf[mt], vf[nt], acc[mt][nt], 0, 0, 0);
    __syncthreads();
  }

  float sums[4][4];
#pragma unroll
  for (int mt = 0; mt < 4; ++mt)
#pragma unroll
    for (int r = 0; r < 4; ++r) sums[mt][r] = 0.f;
#pragma unroll
  for (int mt = 0; mt < 4; ++mt)
#pragma unroll
    for (int nt = 0; nt < 7; ++nt)
#pragma unroll
      for (int r = 0; r < 4; ++r)
        sums[mt][r] += tanhf(acc[mt][nt][r]) * ql[nt];
#pragma unroll
  for (int mask = 1; mask < 16; mask <<= 1)
#pragma unroll
    for (int mt = 0; mt < 4; ++mt)
#pragma unroll
      for (int r = 0; r < 4; ++r)
        sums[mt][r] += __shfl_xor(sums[mt][r], mask);

  float outv = 0.f;
#pragma unroll
  for (int mt = 0; mt < 4; ++mt)
#pragma unroll
    for (int r = 0; r < 4; ++r)
      if (l15 == mt * 4 + r) outv = sums[mt][r];
  sred[wn][wm * 64 + (l15 >> 2) * 16 + l4 * 4 + (l15 & 3)] = outv;
  __syncthreads();
  if (tid < 256) score[row0 + tid] = sred[0][tid] + sred[1][tid];
}

// ---------------------------------------------------------------------------
// K2: softmax over the N (titles) axis, per (b,t).
// ---------------------------------------------------------------------------
__global__ void k2_softmax_n(const float* __restrict__ score, float* __restrict__ alpha) {
  int i = blockIdx.x * 256 + threadIdx.x;
  if (i >= BB * TT) return;
  int b = i / TT, t = i - b * TT;
  int base = b * (NN * TT) + t;
  float m = -1e30f;
  for (int n = 0; n < NN; ++n) m = fmaxf(m, score[base + n * TT]);
  float s = 0.f;
  for (int n = 0; n < NN; ++n) s += __expf(score[base + n * TT] - m);
  float inv = 1.f / s;
  for (int n = 0; n < NN; ++n)
    alpha[base + n * TT] = __expf(score[base + n * TT] - m) * inv;
}

// ---------------------------------------------------------------------------
// K3: e[bn,f] = sum_t alpha[bn,t] * C[bn,t,f]  -> bf16 [3200][416] padded
// ---------------------------------------------------------------------------
__global__ __launch_bounds__(256) void k3_wsum(
    const float* __restrict__ alpha, const __hip_bfloat16* __restrict__ C,
    __hip_bfloat16* __restrict__ Ebf) {
  __shared__ float al[TT];
  const int bn = blockIdx.x;
  const int tid = threadIdx.x;
  if (tid < TT) al[tid] = alpha[bn * TT + tid];
  __syncthreads();
  for (int f = tid; f < 416; f += 256) {
    float s = 0.f;
    if (f < FN) {
#pragma unroll
      for (int t = 0; t < TT; ++t)
        s = fmaf(al[t], __bfloat162float(C[((size_t)bn * TT + t) * 416 + f]), s);
    }
    Ebf[(size_t)bn * 416 + f] = __float2bfloat16(s);
  }
}

// ---------------------------------------------------------------------------
// K4: gx = e @ W_ih^T + b_ih via bf16 MFMA. M=3200, N=1344(pad), K=416.
// ---------------------------------------------------------------------------
__global__ __launch_bounds__(512) void k4_gx_mfma(
    const __hip_bfloat16* __restrict__ Ebf,   // [3200][416]
    const __hip_bfloat16* __restrict__ Wih,   // [1344][416]
    const float* __restrict__ b_ih,           // [1200]
    float* __restrict__ gx)                   // [3200][1200]
{
  __shared__ __align__(16) ushort Alds[128 * 40];
  __shared__ __align__(16) ushort Blds[448 * 40];
  const int tid = threadIdx.x;
  const int lane = tid & 63, wid = tid >> 6;
  const int wm = wid >> 2, wn = wid & 3;
  const int l15 = lane & 15, l4 = lane >> 4;
  const int mb = blockIdx.x / 3;
  const int nb = blockIdx.x - mb * 3;
  const int row0 = mb * 128;
  const int n0 = nb * 448;

  f32x4 acc[4][7];
#pragma unroll
  for (int nt = 0; nt < 7; ++nt) {
    int j = n0 + wn * 112 + nt * 16 + l15;
    float bj = (j < 1200) ? b_ih[j] : 0.f;
#pragma unroll
    for (int mt = 0; mt < 4; ++mt) {
      acc[mt][nt][0] = bj; acc[mt][nt][1] = bj;
      acc[mt][nt][2] = bj; acc[mt][nt][3] = bj;
    }
  }

  const int ar = tid >> 2, ac = tid & 3;
  for (int ks = 0; ks < 13; ++ks) {
    *(uint4*)(&Alds[ar * 40 + ac * 8]) =
        *(const uint4*)((const ushort*)Ebf + (size_t)(row0 + ar) * 416 + ks * 32 + ac * 8);
    for (int idx = tid; idx < 1792; idx += 512) {
      int r = idx >> 2, c = idx & 3;
      *(uint4*)(&Blds[r * 40 + c * 8]) =
          *(const uint4*)((const ushort*)Wih + (size_t)(n0 + r) * 416 + ks * 32 + c * 8);
    }
    __syncthreads();
    bf16x8 af[4];
#pragma unroll
    for (int mt = 0; mt < 4; ++mt)
      af[mt] = *(const bf16x8*)(&Alds[(wm * 64 + mt * 16 + l15) * 40 + l4 * 8]);
#pragma unroll
    for (int nt = 0; nt < 7; ++nt) {
      bf16x8 bfr = *(const bf16x8*)(&Blds[(wn * 112 + nt * 16 + l15) * 40 + l4 * 8]);
#pragma unroll
      for (int mt = 0; mt < 4; ++mt)
        acc[mt][nt] = __builtin_amdgcn_mfma_f32_16x16x32_bf16(af[mt], bfr, acc[mt][nt], 0, 0, 0);
    }
    __syncthreads();
  }

#pragma unroll
  for (int mt = 0; mt < 4; ++mt) {
    int row = row0 + wm * 64 + mt * 16 + l4 * 4;
#pragma unroll
    for (int nt = 0; nt < 7; ++nt) {
      int j = n0 + wn * 112 + nt * 16 + l15;
      if (j < 1200) {
#pragma unroll
        for (int r = 0; r < 4; ++r)
          gx[(size_t)(row + r) * 1200 + j] = acc[mt][nt][r];
      }
    }
  }
}

// ---------------------------------------------------------------------------
// GRU step v3: 256-block chain (proven best structure) with wide-instruction
// GEMV. Wpk is g-contiguous: each thread reads its 1600B W row as 100 float4
// (8x fewer VMEM instr than the strided layout; L2-hot, L1 catches row
// reuse). h read as block-uniform float4 global loads (one L1-broadcast
// request per wave — removes the 800-instr LDS broadcast storm that bound
// the old chain). 4 independent FMA chains. Final step writes out directly.
// ---------------------------------------------------------------------------
__global__ __launch_bounds__(256) void k5_step(
    const float* __restrict__ h_prev, float* __restrict__ h_next,
    const float* __restrict__ Wpk,    // [8 gc][150 jl][400 g]
    const float* __restrict__ b_hh,
    const float* __restrict__ gx, const int* __restrict__ hist_len,
    float* __restrict__ out, int step)
{
  const int gc = blockIdx.x & 7;
  const int bg = blockIdx.x >> 3;
  const int tid = threadIdx.x;
  __shared__ float ghl[2][3][50];

  if (tid < 150) {
    const float* h0p = h_prev + (size_t)(2 * bg) * GG;   // block-uniform
    const float* h1p = h0p + GG;
    const float* wp = Wpk + ((size_t)gc * 150 + tid) * 400;
    float a00 = 0.f, a01 = 0.f, a10 = 0.f, a11 = 0.f;
#pragma unroll 8
    for (int g4 = 0; g4 < 100; ++g4) {
      float4 w  = *(const float4*)(wp + g4 * 4);
      float4 ha = *(const float4*)(h0p + g4 * 4);        // uniform -> L1 bcast
      float4 hb = *(const float4*)(h1p + g4 * 4);
      a00 = fmaf(w.x, ha.x, a00); a01 = fmaf(w.y, ha.y, a01);
      a00 = fmaf(w.z, ha.z, a00); a01 = fmaf(w.w, ha.w, a01);
      a10 = fmaf(w.x, hb.x, a10); a11 = fmaf(w.y, hb.y, a11);
      a10 = fmaf(w.z, hb.z, a10); a11 = fmaf(w.w, hb.w, a11);
    }
    int gate = tid / 50, gl = tid - gate * 50;
    float bb = b_hh[gate * 400 + gc * 50 + gl];
    ghl[0][gate][gl] = a00 + a01 + bb;
    ghl[1][gate][gl] = a10 + a11 + bb;
  }
  __syncthreads();

  if (tid < 100) {
    int b = tid / 50, gl = tid - (tid / 50) * 50;
    int babs = 2 * bg + b;
    int g = gc * 50 + gl;
    const float* gxp = gx + ((size_t)babs * NN + step) * 1200;
    float xr = gxp[g], xz = gxp[400 + g], xn = gxp[800 + g];
    float hr = ghl[b][0][gl], hz = ghl[b][1][gl], hn = ghl[b][2][gl];
    float r = sigf(xr + hr);
    float z = sigf(xz + hz);
    float nv = tanhf(xn + r * hn);
    float hold = h_prev[(size_t)babs * GG + g];
    float hnew = (1.f - z) * nv + z * hold;
    float hres = (step < hist_len[babs]) ? hnew : hold;
    h_next[(size_t)babs * GG + g] = hres;
    if (step == NN - 1) out[(size_t)babs * GG + g] = hres;
  }
}

// ---------------------------------------------------------------------------
extern "C" void kernel_launch(void* const* d_in, const int* in_sizes, int n_in,
                              void* d_out, int out_size, void* d_ws, size_t ws_size,
                              hipStream_t stream) {
  const int*   user_id   = (const int*)d_in[0];
  const int*   title     = (const int*)d_in[1];
  const int*   hist_len  = (const int*)d_in[2];
  const float* word_emb  = (const float*)d_in[3];
  const float* conv_w    = (const float*)d_in[4];
  const float* conv_b    = (const float*)d_in[5];
  const float* v         = (const float*)d_in[6];
  const float* vb        = (const float*)d_in[7];
  const float* q         = (const float*)d_in[8];
  const float* user_emb  = (const float*)d_in[9];
  const float* W_ih      = (const float*)d_in[10];
  const float* W_hh      = (const float*)d_in[11];
  const float* b_ih      = (const float*)d_in[12];
  const float* b_hh      = (const float*)d_in[13];
  float* out = (float*)d_out;

  char* ws = (char*)d_ws;
  size_t off = 0;
  auto take = [&](size_t bytes) {
    char* p = ws + off;
    off = (off + bytes + 255) & ~(size_t)255;
    return p;
  };
  __hip_bfloat16* C      = (__hip_bfloat16*)take((size_t)BB * NN * TT * 416 * 2);  // 79.9MB
  float* score  = (float*)take((size_t)BB * NN * TT * 4);
  float* alpha  = (float*)take((size_t)BB * NN * TT * 4);
  __hip_bfloat16* Ebf    = (__hip_bfloat16*)take((size_t)BB * NN * 416 * 2);
  __hip_bfloat16* Wih_bf = (__hip_bfloat16*)take((size_t)1344 * 416 * 2);
  float* Wpk    = (float*)take((size_t)8 * 150 * 400 * 4);
  float* gx     = (float*)take((size_t)BB * NN * 1200 * 4);
  float* h0     = (float*)take((size_t)BB * GG * 4);
  float* h1     = (float*)take((size_t)BB * GG * 4);
  __hip_bfloat16* emb_bf = (__hip_bfloat16*)take((size_t)50000 * 320 * 2);        // 32MB
  __hip_bfloat16* WT2    = (__hip_bfloat16*)take((size_t)30 * 448 * 32 * 2);      // 860KB
  __hip_bfloat16* vT2    = (__hip_bfloat16*)take((size_t)13 * 224 * 32 * 2);      // 186KB
  float* qp     = (float*)take(224 * 4);
  float* vbp    = (float*)take(224 * 4);
  (void)ws_size;

  k_prep_all<<<6204, 256, 0, stream>>>(W_hh, conv_w, v, q, vb, W_ih, user_id,
                                       user_emb, Wpk, WT2, vT2, qp, vbp,
                                       Wih_bf, h0);
  k_prep_emb<<<(50000 * 80 + 255) / 256, 256, 0, stream>>>(word_emb, emb_bf);

  k_conv<<<BB * NN / 2, 256, 0, stream>>>(title, emb_bf, WT2, conv_b, C);
  k_attn<<<BB * NN * TT / 256, 512, 0, stream>>>(C, vT2, vbp, qp, score);
  k2_softmax_n<<<(BB * TT + 255) / 256, 256, 0, stream>>>(score, alpha);
  k3_wsum<<<BB * NN, 256, 0, stream>>>(alpha, C, Ebf);
  k4_gx_mfma<<<75, 512, 0, stream>>>(Ebf, Wih_bf, b_ih, gx);

  float* hbuf[2] = {h0, h1};
  for (int step = 0; step < NN; ++step) {
    k5_step<<<256, 256, 0, stream>>>(hbuf[step & 1], hbuf[(step + 1) & 1],
                                     Wpk, b_hh, gx, hist_len, out, step);
  }
}